// Round 11
// baseline (121.797 us; speedup 1.0000x reference)
//
#include <hip/hip_runtime.h>
#include <hip/hip_bf16.h>
#include <math.h>

#define CC   256
#define NQQ  4096
#define MT   8192

typedef __attribute__((ext_vector_type(8))) short s8v;
typedef __attribute__((ext_vector_type(4))) float f4v;

static __device__ __forceinline__ ushort f2bu(float f) {
    __hip_bfloat16 h = __float2bfloat16(f);
    return *reinterpret_cast<ushort*>(&h);
}

// Fragment layout for weights: Wf[((ntile*8 + kc)*64 + lane)*8 + e]
//   lane l supplies B rows (n = ntile*16 + (l&15)), k = kc*32 + (l>>4)*8 + e

// ======== setup: pos tables/refpts/tgt-init + weight->fragment transpose + fuse ========
__global__ __launch_bounds__(256) void setup_kernel(
        const float* __restrict__ qemb, const float* __restrict__ rw,
        const float* __restrict__ rb,
        const float* __restrict__ feat0, const float* __restrict__ feat1,
        const float* __restrict__ fl,
        const float* __restrict__ val_w, const float* __restrict__ off_w,
        const float* __restrict__ aw_w,  const float* __restrict__ out_w,
        const float* __restrict__ f1_w,  const float* __restrict__ f2_w,
        const float* __restrict__ off_b, const float* __restrict__ aw_b,
        float* __restrict__ posY, float* __restrict__ posX,
        float* __restrict__ refp, float* __restrict__ tgt,
        ushort* __restrict__ wval01, ushort* __restrict__ wvalS,
        ushort* __restrict__ woffaw, ushort* __restrict__ wout,
        ushort* __restrict__ wf1, ushort* __restrict__ wf2,
        float* __restrict__ bOA, ushort* __restrict__ fused) {
    __shared__ float tl[64][65];
    int bid = blockIdx.x;
    int t = threadIdx.x;
    if (bid < 64) {                         // pos tables: posY[64][128], posX[64][128]
        int idx = bid * 256 + t;            // 0..16383
        int tbl = idx >> 13;
        int rem = idx & 8191;
        int ci = rem >> 7;                  // coord index 0..63
        int c = rem & 127;
        int k = c >> 1;
        float coord = (float)(ci + 1) * (6.28318530717958647692f / (64.0f + 1e-6f));
        float v = coord * exp2f(-0.20762050593046016f * (float)k);
        float val = (c & 1) ? __cosf(v) : __sinf(v);
        (tbl == 0 ? posY : posX)[ci * 128 + c] = val;
        return;
    }
    if (bid < 1088) {                       // refpts
        int row = (bid - 64) * 4 + (t >> 6);
        int l = t & 63;
        float4 v = *(const float4*)(qemb + (size_t)row * 512 + l * 4);
        float a0 = v.x * rw[(l * 4 + 0) * 2] + v.y * rw[(l * 4 + 1) * 2]
                 + v.z * rw[(l * 4 + 2) * 2] + v.w * rw[(l * 4 + 3) * 2];
        float a1 = v.x * rw[(l * 4 + 0) * 2 + 1] + v.y * rw[(l * 4 + 1) * 2 + 1]
                 + v.z * rw[(l * 4 + 2) * 2 + 1] + v.w * rw[(l * 4 + 3) * 2 + 1];
        #pragma unroll
        for (int o = 32; o > 0; o >>= 1) { a0 += __shfl_xor(a0, o); a1 += __shfl_xor(a1, o); }
        if (l == 0) {
            refp[row * 2 + 0] = 1.0f / (1.0f + __expf(-(a0 + rb[0])));
            refp[row * 2 + 1] = 1.0f / (1.0f + __expf(-(a1 + rb[1])));
        }
        return;
    }
    if (bid < 3136) {                       // tgt init
        int idx = (bid - 1088) * 256 + t;
        int c4 = idx & 63;
        int q = (idx >> 6) & (NQQ - 1);
        *(float4*)(tgt + (size_t)idx * 4) = *(const float4*)(qemb + (size_t)q * 512 + 256 + c4 * 4);
        return;
    }
    if (bid < 3444) {                       // weight prep -> fragment layout
        int wb = bid - 3136;
        if (wb >= 304) {
            int layer = wb - 304;
            if (t < 192)
                bOA[layer * 192 + t] = (t < 128) ? off_b[layer * 128 + t]
                                                 : aw_b[layer * 64 + (t - 128)];
            return;
        }
        const float* src; ushort* dstF; int srcStride, ntb, kcb;
        if (wb < 32) {
            int nt = wb & 7, kt = wb >> 3;
            int layer = nt >> 2, nn = (nt & 3) * 64;
            src = val_w + (size_t)layer * 65536 + (size_t)kt * 64 * 256 + nn; srcStride = 256;
            dstF = wval01; ntb = nt * 4; kcb = kt * 2;
        } else if (wb < 64) {
            int b = wb - 32; int layer = b >> 4; int kt = (b >> 2) & 3; int nt = b & 3;
            src = val_w + (size_t)(2 + layer) * 65536 + (size_t)kt * 64 * 256 + nt * 64; srcStride = 256;
            dstF = wvalS + (size_t)layer * 65536; ntb = nt * 4; kcb = kt * 2;
        } else if (wb < 112) {
            int b = wb - 64; int layer = b / 12; int rem = b % 12; int kt = rem / 3; int nt = rem % 3;
            if (nt < 2) { src = off_w + (size_t)layer * 256 * 128 + (size_t)kt * 64 * 128 + nt * 64; srcStride = 128; }
            else        { src = aw_w  + (size_t)layer * 256 * 64  + (size_t)kt * 64 * 64;            srcStride = 64;  }
            dstF = woffaw + (size_t)layer * 49152; ntb = nt * 4; kcb = kt * 2;
        } else {
            int b = wb - 112; int fam = b >> 6; int bb = b & 63;
            int layer = bb >> 4; int kt = (bb >> 2) & 3; int nt = bb & 3;
            const float* s0 = (fam == 0) ? out_w : ((fam == 1) ? f1_w : f2_w);
            ushort* d0      = (fam == 0) ? wout  : ((fam == 1) ? wf1  : wf2);
            src = s0 + (size_t)layer * 65536 + (size_t)kt * 64 * 256 + nt * 64; srcStride = 256;
            dstF = d0 + (size_t)layer * 65536; ntb = nt * 4; kcb = kt * 2;
        }
        int r = t >> 6, c = t & 63;
        #pragma unroll
        for (int rr = 0; rr < 64; rr += 4)                 // tl[k_local][n_local]
            tl[rr + r][c] = src[(size_t)(rr + r) * srcStride + c];
        __syncthreads();
        int l = t >> 2;               // 0..63 (lane of fragment)
        int e0 = (t & 3) * 2;         // 0,2,4,6
        int frow = l & 15;            // n within 16-tile
        int fcol = (l >> 4) * 8;      // k offset within chunk
        #pragma unroll
        for (int s = 0; s < 8; s++) {
            int ntl = s & 3, kcl = s >> 2;
            int ntile = ntb + ntl, kc = kcb + kcl;
            ushort2 val;
            val.x = f2bu(tl[kcl * 32 + fcol + e0    ][ntl * 16 + frow]);
            val.y = f2bu(tl[kcl * 32 + fcol + e0 + 1][ntl * 16 + frow]);
            *(ushort2*)(dstF + (((size_t)ntile * 8 + kc) * 64 + l) * 8 + e0) = val;
        }
        return;
    }
    {                                       // fuse
        int fb = bid - 3444;
        int b = fb >> 8;
        int c0 = ((fb >> 6) & 3) * 64;
        int q0 = (fb & 63) * 64;
        int r = t >> 6, c = t & 63;
        #pragma unroll
        for (int rr = 0; rr < 64; rr += 4) {
            int ch = c0 + rr + r;
            float l0 = fl[ch], l1 = fl[CC + ch];
            float m = fmaxf(l0, l1);
            float e0 = __expf(l0 - m), e1 = __expf(l1 - m);
            float inv = 1.0f / (e0 + e1);
            size_t o = ((size_t)b * CC + ch) * NQQ + q0 + c;
            tl[rr + r][c] = (feat0[o] * e0 + feat1[o] * e1) * inv;
        }
        __syncthreads();
        #pragma unroll
        for (int rr = 0; rr < 64; rr += 4)
            fused[((size_t)(b * NQQ + q0 + rr + r)) * CC + c0 + c] = f2bu(tl[c][rr + r]);
    }
}

// ======== projection GEMM: 32-row tiles, 1024 threads, 1 n-tile/wave, 2 row-groups ======
__global__ __launch_bounds__(1024, 4) void pgemm(const ushort* __restrict__ Abf,
        const ushort* __restrict__ Wf, const float* __restrict__ bias,
        ushort* __restrict__ Cb, int NS) {
    __shared__ ushort Abuf[32 * 264];
    const int t = threadIdx.x;
    const int m0 = blockIdx.x * 32;
    const int cb0 = blockIdx.y * 256;
    const int ntb = blockIdx.y * 16;
    {
        const int rg = t >> 5, c0 = (t & 31) * 8;
        *(int4*)(Abuf + rg * 264 + c0) = *(const int4*)(Abf + (size_t)(m0 + rg) * 256 + c0);
    }
    __syncthreads();
    const int l = t & 63, w = t >> 6;
    const int fr = l & 15, fk8 = (l >> 4) * 8, rb = (l >> 4) * 4;
    f4v acc[2] = {};
    #pragma unroll
    for (int kc = 0; kc < 8; kc++) {
        s8v b = *(const s8v*)(Wf + (((size_t)(ntb + w) * 8 + kc) * 64 + l) * 8);
        s8v a0 = *(const s8v*)(Abuf + fr * 264 + kc * 32 + fk8);
        s8v a1 = *(const s8v*)(Abuf + (16 + fr) * 264 + kc * 32 + fk8);
        acc[0] = __builtin_amdgcn_mfma_f32_16x16x32_bf16(a0, b, acc[0], 0, 0, 0);
        acc[1] = __builtin_amdgcn_mfma_f32_16x16x32_bf16(a1, b, acc[1], 0, 0, 0);
    }
    int gcol = cb0 + w * 16 + fr;
    float bz = bias[gcol];
    #pragma unroll
    for (int g = 0; g < 2; g++)
        #pragma unroll
        for (int r = 0; r < 4; r++)
            Cb[(size_t)(m0 + g * 16 + rb + r) * NS + gcol] = f2bu(acc[g][r] + bz);
}

// ======== full decoder layer: 32 rows/block, 1024 threads, B-fragment prefetch ========
template<int SELF, int EMITVAL>
__global__ __launch_bounds__(1024, 4) void layer_kernel(
        float* __restrict__ tgt, const float* __restrict__ posq,
        const float* __restrict__ posY, const float* __restrict__ posX,
        const float* __restrict__ g1, const float* __restrict__ b1,
        const ushort* __restrict__ woffawL, const float* __restrict__ bOAL,
        const ushort* __restrict__ value, int vstride,
        const float* __restrict__ refp,
        const ushort* __restrict__ woutL, const float* __restrict__ out_bL,
        const float* __restrict__ g2, const float* __restrict__ b2,
        const ushort* __restrict__ wf1L, const float* __restrict__ f1_bL,
        const ushort* __restrict__ wf2L, const float* __restrict__ f2_bL,
        const ushort* __restrict__ wvalN, const float* __restrict__ val_bN,
        ushort* __restrict__ valueOut) {
    __shared__ ushort Abuf[32 * 264];          // 16.9 KB
    __shared__ float Slds[32 * 204];           // 26.1 KB
    __shared__ float pred[2][16][32];          // 4 KB
    __shared__ float mrs[2][32];
    const int t = threadIdx.x;
    const int m0 = blockIdx.x * 32;
    const int l = t & 63, w = t >> 6;          // wave 0..15
    const int fr = l & 15, fk8 = (l >> 4) * 8, rb = (l >> 4) * 4;
    const int gcol = w * 16 + fr;

    // prefetched B fragments for the next GEMM phase (32 VGPR)
    s8v breg[8];
    // prefetch offaw B (phase 1) at earliest point
    {
        int nt = (w < 12) ? w : 0;
        #pragma unroll
        for (int kc = 0; kc < 8; kc++)
            breg[kc] = *(const s8v*)(woffawL + (((size_t)nt * 8 + kc) * 64 + l) * 8);
    }

    // ---- phase 0: stage query tile (LN1+qemb | +pos tables), 8 cols/thread ----
    {
        const int rg = t >> 5, c0 = (t & 31) * 8;
        int m = m0 + rg, q = m & (NQQ - 1);
        const float* src = tgt + (size_t)m * 256 + c0;
        float fv[8];
        *(float4*)&fv[0] = *(const float4*)src;
        *(float4*)&fv[4] = *(const float4*)(src + 4);
        if (!SELF) {
            float s = 0.0f;
            #pragma unroll
            for (int k = 0; k < 8; k++) s += fv[k];
            s += __shfl_xor(s, 1); s += __shfl_xor(s, 2); s += __shfl_xor(s, 4);
            s += __shfl_xor(s, 8); s += __shfl_xor(s, 16);
            float mean = s * (1.0f / 256.0f);
            float s2 = 0.0f;
            #pragma unroll
            for (int k = 0; k < 8; k++) { float d = fv[k] - mean; s2 += d * d; }
            s2 += __shfl_xor(s2, 1); s2 += __shfl_xor(s2, 2); s2 += __shfl_xor(s2, 4);
            s2 += __shfl_xor(s2, 8); s2 += __shfl_xor(s2, 16);
            float rstd = rsqrtf(s2 * (1.0f / 256.0f) + 1e-5f);
            const float* ep = posq + (size_t)q * 512 + c0;     // qemb[:, :C]
            #pragma unroll
            for (int k = 0; k < 8; k++)
                fv[k] = (fv[k] - mean) * rstd * g1[c0 + k] + b1[c0 + k] + ep[k];
        } else {
            const float* ep = (c0 < 128) ? (posY + (q >> 6) * 128 + c0)
                                         : (posX + (q & 63) * 128 + (c0 - 128));
            #pragma unroll
            for (int k = 0; k < 8; k++) fv[k] += ep[k];
        }
        ushort tmp[8];
        #pragma unroll
        for (int k = 0; k < 8; k++) tmp[k] = f2bu(fv[k]);
        *(int4*)(Abuf + rg * 264 + c0) = *(const int4*)tmp;
    }
    __syncthreads();

    // ---- phase 1: offaw GEMM (prefetched B), then prefetch wout ----
    {
        f4v oacc[2] = {};
        if (w < 12) {
            #pragma unroll
            for (int kc = 0; kc < 8; kc++) {
                s8v a0 = *(const s8v*)(Abuf + fr * 264 + kc * 32 + fk8);
                s8v a1 = *(const s8v*)(Abuf + (16 + fr) * 264 + kc * 32 + fk8);
                oacc[0] = __builtin_amdgcn_mfma_f32_16x16x32_bf16(a0, breg[kc], oacc[0], 0, 0, 0);
                oacc[1] = __builtin_amdgcn_mfma_f32_16x16x32_bf16(a1, breg[kc], oacc[1], 0, 0, 0);
            }
        }
        #pragma unroll
        for (int kc = 0; kc < 8; kc++)      // prefetch phase-3 B (wout)
            breg[kc] = *(const s8v*)(woutL + (((size_t)w * 8 + kc) * 64 + l) * 8);
        if (w < 12) {
            float bz = bOAL[gcol];
            #pragma unroll
            for (int g = 0; g < 2; g++)
                #pragma unroll
                for (int r = 0; r < 4; r++)
                    Slds[(g * 16 + rb + r) * 204 + gcol] = oacc[g][r] + bz;
        }
    }
    __syncthreads();

    // ---- phase 2: softmax + bilinear sampling; prefetch residual tgt ----
    float tres[2][4];
    {
        const int row = t >> 5, h = (t >> 2) & 7, d8 = t & 3;
        int m = m0 + row, q = m & (NQQ - 1), bidx = m >> 12;
        float rxs, rys;
        if (SELF) { rxs = (float)(q & 63) * 64.0f + 32.0f; rys = (float)(q >> 6) * 64.0f + 32.0f; }
        else      { rxs = refp[q * 2] * 64.0f;             rys = refp[q * 2 + 1] * 64.0f; }
        const float* oa = Slds + row * 204;
        float lg[8];
        #pragma unroll
        for (int p = 0; p < 8; p++) lg[p] = oa[128 + h * 8 + p];
        float mx = lg[0];
        #pragma unroll
        for (int p = 1; p < 8; p++) mx = fmaxf(mx, lg[p]);
        float wg[8], wsum = 0.0f;
        #pragma unroll
        for (int p = 0; p < 8; p++) { wg[p] = __expf(lg[p] - mx); wsum += wg[p]; }
        float inv = 1.0f / wsum;
        const float* offp = oa + h * 16;
        const ushort* vb = value + (size_t)bidx * NQQ * vstride + h * 32 + d8 * 8;
        float acc[8] = {};
        #pragma unroll
        for (int p = 0; p < 8; p++) {
            float px = rxs + offp[p * 2]     - 0.5f;
            float py = rys + offp[p * 2 + 1] - 0.5f;
            float x0f = floorf(px), y0f = floorf(py);
            float lx = px - x0f, ly = py - y0f;
            int x0 = (int)x0f, y0 = (int)y0f;
            float wgt = wg[p] * inv;
            float w00 = (1 - lx) * (1 - ly) * wgt, w10 = lx * (1 - ly) * wgt;
            float w01 = (1 - lx) * ly * wgt,       w11 = lx * ly * wgt;
            #pragma unroll
            for (int cn = 0; cn < 4; cn++) {
                int xi = x0 + (cn & 1), yi = y0 + (cn >> 1);
                float wc = (cn == 0) ? w00 : (cn == 1) ? w10 : (cn == 2) ? w01 : w11;
                if (xi >= 0 && xi < 64 && yi >= 0 && yi < 64) {
                    uint4 uv = *(const uint4*)(vb + (size_t)(yi * 64 + xi) * vstride);
                    uint ua[4] = {uv.x, uv.y, uv.z, uv.w};
                    #pragma unroll
                    for (int k = 0; k < 4; k++) {
                        uint lo = ua[k] << 16;
                        uint hi = ua[k] & 0xffff0000u;
                        acc[k * 2 + 0] += wc * *reinterpret_cast<float*>(&lo);
                        acc[k * 2 + 1] += wc * *reinterpret_cast<float*>(&hi);
                    }
                }
            }
        }
        ushort pk[8];
        #pragma unroll
        for (int k = 0; k < 8; k++) pk[k] = f2bu(acc[k]);
        *(int4*)(Abuf + row * 264 + h * 32 + d8 * 8) = *(const int4*)pk;
        // prefetch phase-3 residual reads (global, independent of Abuf)
        #pragma unroll
        for (int g = 0; g < 2; g++)
            #pragma unroll
            for (int r = 0; r < 4; r++)
                tres[g][r] = tgt[(size_t)(m0 + g * 16 + rb + r) * 256 + gcol];
    }
    __syncthreads();

    // ---- phase 3: out-proj + residual + LN2 stats; prefetch wf1 ----
    float v[2][4];
    {
        f4v acc[2] = {};
        #pragma unroll
        for (int kc = 0; kc < 8; kc++) {
            s8v a0 = *(const s8v*)(Abuf + fr * 264 + kc * 32 + fk8);
            s8v a1 = *(const s8v*)(Abuf + (16 + fr) * 264 + kc * 32 + fk8);
            acc[0] = __builtin_amdgcn_mfma_f32_16x16x32_bf16(a0, breg[kc], acc[0], 0, 0, 0);
            acc[1] = __builtin_amdgcn_mfma_f32_16x16x32_bf16(a1, breg[kc], acc[1], 0, 0, 0);
        }
        #pragma unroll
        for (int kc = 0; kc < 8; kc++)      // prefetch phase-4 B (wf1)
            breg[kc] = *(const s8v*)(wf1L + (((size_t)w * 8 + kc) * 64 + l) * 8);
        float ls[2][4], lq[2][4];
        float bz = out_bL[gcol];
        #pragma unroll
        for (int g = 0; g < 2; g++)
            #pragma unroll
            for (int r = 0; r < 4; r++) {
                float tv = tres[g][r] + acc[g][r] + bz;
                v[g][r] = tv;
                ls[g][r] = tv;
                lq[g][r] = tv * tv;
            }
        #pragma unroll
        for (int o = 1; o < 16; o <<= 1)
            #pragma unroll
            for (int g = 0; g < 2; g++)
                #pragma unroll
                for (int r = 0; r < 4; r++) {
                    ls[g][r] += __shfl_xor(ls[g][r], o);
                    lq[g][r] += __shfl_xor(lq[g][r], o);
                }
        if (fr == 0)
            #pragma unroll
            for (int g = 0; g < 2; g++)
                #pragma unroll
                for (int r = 0; r < 4; r++) {
                    pred[0][w][g * 16 + rb + r] = ls[g][r];
                    pred[1][w][g * 16 + rb + r] = lq[g][r];
                }
    }
    __syncthreads();
    if (t < 32) {
        float s = 0.0f, sq = 0.0f;
        #pragma unroll
        for (int ww = 0; ww < 16; ww++) { s += pred[0][ww][t]; sq += pred[1][ww][t]; }
        float mean = s * (1.0f / 256.0f);
        float var = sq * (1.0f / 256.0f) - mean * mean;
        mrs[0][t] = mean;
        mrs[1][t] = rsqrtf(var + 1e-5f);
    }
    __syncthreads();

    // ---- LN2 normalize -> Abuf ----
    #pragma unroll
    for (int g = 0; g < 2; g++)
        #pragma unroll
        for (int r = 0; r < 4; r++) {
            int rloc = g * 16 + rb + r;
            Abuf[rloc * 264 + gcol] = f2bu((v[g][r] - mrs[0][rloc]) * mrs[1][rloc] * g2[gcol] + b2[gcol]);
        }
    __syncthreads();

    // ---- phase 4: FFN1 + relu -> Abuf; prefetch wf2 ----
    {
        f4v acc[2] = {};
        #pragma unroll
        for (int kc = 0; kc < 8; kc++) {
            s8v a0 = *(const s8v*)(Abuf + fr * 264 + kc * 32 + fk8);
            s8v a1 = *(const s8v*)(Abuf + (16 + fr) * 264 + kc * 32 + fk8);
            acc[0] = __builtin_amdgcn_mfma_f32_16x16x32_bf16(a0, breg[kc], acc[0], 0, 0, 0);
            acc[1] = __builtin_amdgcn_mfma_f32_16x16x32_bf16(a1, breg[kc], acc[1], 0, 0, 0);
        }
        #pragma unroll
        for (int kc = 0; kc < 8; kc++)      // prefetch phase-5 B (wf2)
            breg[kc] = *(const s8v*)(wf2L + (((size_t)w * 8 + kc) * 64 + l) * 8);
        __syncthreads();
        float bz = f1_bL[gcol];
        #pragma unroll
        for (int g = 0; g < 2; g++)
            #pragma unroll
            for (int r = 0; r < 4; r++)
                Abuf[(g * 16 + rb + r) * 264 + gcol] = f2bu(fmaxf(acc[g][r] + bz, 0.0f));
    }
    __syncthreads();

    // ---- phase 5: FFN2 + relu + residual, final write (+ restage if EMITVAL) ----
    {
        f4v acc[2] = {};
        #pragma unroll
        for (int kc = 0; kc < 8; kc++) {
            s8v a0 = *(const s8v*)(Abuf + fr * 264 + kc * 32 + fk8);
            s8v a1 = *(const s8v*)(Abuf + (16 + fr) * 264 + kc * 32 + fk8);
            acc[0] = __builtin_amdgcn_mfma_f32_16x16x32_bf16(a0, breg[kc], acc[0], 0, 0, 0);
            acc[1] = __builtin_amdgcn_mfma_f32_16x16x32_bf16(a1, breg[kc], acc[1], 0, 0, 0);
        }
        if (EMITVAL) {
            #pragma unroll
            for (int kc = 0; kc < 8; kc++)  // prefetch phase-6 B (wvalN)
                breg[kc] = *(const s8v*)(wvalN + (((size_t)w * 8 + kc) * 64 + l) * 8);
            __syncthreads();                // drain Abuf reads before overwrite
        }
        float bz = f2_bL[gcol];
        #pragma unroll
        for (int g = 0; g < 2; g++)
            #pragma unroll
            for (int r = 0; r < 4; r++) {
                float fin = v[g][r] + fmaxf(acc[g][r] + bz, 0.0f);
                tgt[(size_t)(m0 + g * 16 + rb + r) * 256 + gcol] = fin;
                if (EMITVAL) Abuf[(g * 16 + rb + r) * 264 + gcol] = f2bu(fin);
            }
    }
    if (EMITVAL) {
        __syncthreads();
        // ---- phase 6: next layer's value projection from in-LDS tgt ----
        f4v acc[2] = {};
        #pragma unroll
        for (int kc = 0; kc < 8; kc++) {
            s8v a0 = *(const s8v*)(Abuf + fr * 264 + kc * 32 + fk8);
            s8v a1 = *(const s8v*)(Abuf + (16 + fr) * 264 + kc * 32 + fk8);
            acc[0] = __builtin_amdgcn_mfma_f32_16x16x32_bf16(a0, breg[kc], acc[0], 0, 0, 0);
            acc[1] = __builtin_amdgcn_mfma_f32_16x16x32_bf16(a1, breg[kc], acc[1], 0, 0, 0);
        }
        float bz = val_bN[gcol];
        #pragma unroll
        for (int g = 0; g < 2; g++)
            #pragma unroll
            for (int r = 0; r < 4; r++)
                valueOut[(size_t)(m0 + g * 16 + rb + r) * 256 + gcol] = f2bu(acc[g][r] + bz);
    }
}

extern "C" void kernel_launch(void* const* d_in, const int* in_sizes, int n_in,
                              void* d_out, int out_size, void* d_ws, size_t ws_size,
                              hipStream_t stream) {
    const float* feat0 = (const float*)d_in[0];
    const float* feat1 = (const float*)d_in[1];
    const float* qemb  = (const float*)d_in[2];
    const float* ref_w = (const float*)d_in[3];
    const float* ref_b = (const float*)d_in[4];
    const float* fl    = (const float*)d_in[5];
    const float* ln1_g = (const float*)d_in[6];
    const float* ln1_b = (const float*)d_in[7];
    const float* off_w = (const float*)d_in[8];
    const float* off_b = (const float*)d_in[9];
    const float* aw_w  = (const float*)d_in[10];
    const float* aw_b  = (const float*)d_in[11];
    const float* val_w = (const float*)d_in[12];
    const float* val_b = (const float*)d_in[13];
    const float* out_w = (const float*)d_in[14];
    const float* out_b = (const float*)d_in[15];
    const float* ln2_g = (const float*)d_in[16];
    const float* ln2_b = (const float*)d_in[17];
    const float* f1_w  = (const float*)d_in[18];
    const float* f1_b  = (const float*)d_in[19];
    const float* f2_w  = (const float*)d_in[20];
    const float* f2_b  = (const float*)d_in[21];

    float* tgt = (float*)d_out;
    float* ws = (float*)d_ws;
    float* posY    = ws;                                     // 8,192 f32
    float* posX    = posY + 8192;                            // 8,192 f32
    float* refp    = posX + 8192;                            // 8,192 f32
    float* bOA     = refp + 8192;                            // 768 f32
    ushort* value01= (ushort*)(bOA + 768);                   // MT*512
    ushort* valueS0= value01 + (size_t)MT * 512;             // MT*256
    ushort* valueS1= valueS0 + (size_t)MT * 256;             // MT*256
    ushort* wval01 = valueS1 + (size_t)MT * 256;             // 131072
    ushort* wvalS  = wval01 + 131072;                        // 131072
    ushort* woffaw = wvalS + 131072;                         // 196608
    ushort* wout   = woffaw + 196608;                        // 262144
    ushort* wf1    = wout + 262144;                          // 262144
    ushort* wf2    = wf1 + 262144;                           // 262144
    ushort* fused_bf = wf2 + 262144;                         // MT*256

    setup_kernel<<<3956, 256, 0, stream>>>(qemb, ref_w, ref_b, feat0, feat1, fl,
                                           val_w, off_w, aw_w, out_w, f1_w, f2_w,
                                           off_b, aw_b,
                                           posY, posX, refp, tgt,
                                           wval01, wvalS, woffaw, wout, wf1, wf2,
                                           bOA, fused_bf);

    // value projections for both cross layers: [MT,512] bf16
    pgemm<<<dim3(256, 2), 1024, 0, stream>>>(fused_bf, wval01, val_b, value01, 512);

    // L0 (cross)
    layer_kernel<0, 0><<<256, 1024, 0, stream>>>(
        tgt, qemb, posY, posX, ln1_g, ln1_b,
        woffaw, bOA, value01, 512, refp,
        wout, out_b, ln2_g, ln2_b,
        wf1, f1_b, wf2, f2_b,
        nullptr, nullptr, nullptr);
    // L1 (cross, emit value for L2)
    layer_kernel<0, 1><<<256, 1024, 0, stream>>>(
        tgt, qemb, posY, posX, ln1_g + CC, ln1_b + CC,
        woffaw + 49152, bOA + 192, value01 + 256, 512, refp,
        wout + 65536, out_b + CC, ln2_g + CC, ln2_b + CC,
        wf1 + 65536, f1_b + CC, wf2 + 65536, f2_b + CC,
        wvalS, val_b + 2 * CC, valueS0);
    // L2 (self, emit value for L3)
    layer_kernel<1, 1><<<256, 1024, 0, stream>>>(
        tgt, nullptr, posY, posX, nullptr, nullptr,
        woffaw + 2 * 49152, bOA + 2 * 192, valueS0, 256, refp,
        wout + 2 * 65536, out_b + 2 * CC, ln2_g + 2 * CC, ln2_b + 2 * CC,
        wf1 + 2 * 65536, f1_b + 2 * CC, wf2 + 2 * 65536, f2_b + 2 * CC,
        wvalS + 65536, val_b + 3 * CC, valueS1);
    // L3 (self)
    layer_kernel<1, 0><<<256, 1024, 0, stream>>>(
        tgt, nullptr, posY, posX, nullptr, nullptr,
        woffaw + 3 * 49152, bOA + 3 * 192, valueS1, 256, refp,
        wout + 3 * 65536, out_b + 3 * CC, ln2_g + 3 * CC, ln2_b + 3 * CC,
        wf1 + 3 * 65536, f1_b + 3 * CC, wf2 + 3 * 65536, f2_b + 3 * CC,
        nullptr, nullptr, nullptr);
}

// Round 12
// 115.601 us; speedup vs baseline: 1.0536x; 1.0536x over previous
//
#include <hip/hip_runtime.h>
#include <hip/hip_bf16.h>
#include <math.h>

#define CC   256
#define NQQ  4096
#define MT   8192

typedef __attribute__((ext_vector_type(8))) short s8v;
typedef __attribute__((ext_vector_type(4))) float f4v;

static __device__ __forceinline__ ushort f2bu(float f) {
    __hip_bfloat16 h = __float2bfloat16(f);
    return *reinterpret_cast<ushort*>(&h);
}

// Fragment layout for weights: Wf[((ntile*8 + kc)*64 + lane)*8 + e]
//   lane l supplies B rows (n = ntile*16 + (l&15)), k = kc*32 + (l>>4)*8 + e

// ======== setup: pos tables/refpts/tgt-init + weight->fragment transpose + fuse ========
__global__ __launch_bounds__(256) void setup_kernel(
        const float* __restrict__ qemb, const float* __restrict__ rw,
        const float* __restrict__ rb,
        const float* __restrict__ feat0, const float* __restrict__ feat1,
        const float* __restrict__ fl,
        const float* __restrict__ val_w, const float* __restrict__ off_w,
        const float* __restrict__ aw_w,  const float* __restrict__ out_w,
        const float* __restrict__ f1_w,  const float* __restrict__ f2_w,
        const float* __restrict__ off_b, const float* __restrict__ aw_b,
        float* __restrict__ posY, float* __restrict__ posX,
        float* __restrict__ refp, float* __restrict__ tgt,
        ushort* __restrict__ wval01, ushort* __restrict__ wvalS,
        ushort* __restrict__ woffaw, ushort* __restrict__ wout,
        ushort* __restrict__ wf1, ushort* __restrict__ wf2,
        float* __restrict__ bOA, ushort* __restrict__ fused) {
    __shared__ float tl[64][65];
    int bid = blockIdx.x;
    int t = threadIdx.x;
    if (bid < 64) {                         // pos tables: posY[64][128], posX[64][128]
        int idx = bid * 256 + t;            // 0..16383
        int tbl = idx >> 13;
        int rem = idx & 8191;
        int ci = rem >> 7;                  // coord index 0..63
        int c = rem & 127;
        int k = c >> 1;
        float coord = (float)(ci + 1) * (6.28318530717958647692f / (64.0f + 1e-6f));
        float v = coord * exp2f(-0.20762050593046016f * (float)k);
        float val = (c & 1) ? __cosf(v) : __sinf(v);
        (tbl == 0 ? posY : posX)[ci * 128 + c] = val;
        return;
    }
    if (bid < 1088) {                       // refpts
        int row = (bid - 64) * 4 + (t >> 6);
        int l = t & 63;
        float4 v = *(const float4*)(qemb + (size_t)row * 512 + l * 4);
        float a0 = v.x * rw[(l * 4 + 0) * 2] + v.y * rw[(l * 4 + 1) * 2]
                 + v.z * rw[(l * 4 + 2) * 2] + v.w * rw[(l * 4 + 3) * 2];
        float a1 = v.x * rw[(l * 4 + 0) * 2 + 1] + v.y * rw[(l * 4 + 1) * 2 + 1]
                 + v.z * rw[(l * 4 + 2) * 2 + 1] + v.w * rw[(l * 4 + 3) * 2 + 1];
        #pragma unroll
        for (int o = 32; o > 0; o >>= 1) { a0 += __shfl_xor(a0, o); a1 += __shfl_xor(a1, o); }
        if (l == 0) {
            refp[row * 2 + 0] = 1.0f / (1.0f + __expf(-(a0 + rb[0])));
            refp[row * 2 + 1] = 1.0f / (1.0f + __expf(-(a1 + rb[1])));
        }
        return;
    }
    if (bid < 3136) {                       // tgt init
        int idx = (bid - 1088) * 256 + t;
        int c4 = idx & 63;
        int q = (idx >> 6) & (NQQ - 1);
        *(float4*)(tgt + (size_t)idx * 4) = *(const float4*)(qemb + (size_t)q * 512 + 256 + c4 * 4);
        return;
    }
    if (bid < 3444) {                       // weight prep -> fragment layout
        int wb = bid - 3136;
        if (wb >= 304) {
            int layer = wb - 304;
            if (t < 192)
                bOA[layer * 192 + t] = (t < 128) ? off_b[layer * 128 + t]
                                                 : aw_b[layer * 64 + (t - 128)];
            return;
        }
        const float* src; ushort* dstF; int srcStride, ntb, kcb;
        if (wb < 32) {
            int nt = wb & 7, kt = wb >> 3;
            int layer = nt >> 2, nn = (nt & 3) * 64;
            src = val_w + (size_t)layer * 65536 + (size_t)kt * 64 * 256 + nn; srcStride = 256;
            dstF = wval01; ntb = nt * 4; kcb = kt * 2;
        } else if (wb < 64) {
            int b = wb - 32; int layer = b >> 4; int kt = (b >> 2) & 3; int nt = b & 3;
            src = val_w + (size_t)(2 + layer) * 65536 + (size_t)kt * 64 * 256 + nt * 64; srcStride = 256;
            dstF = wvalS + (size_t)layer * 65536; ntb = nt * 4; kcb = kt * 2;
        } else if (wb < 112) {
            int b = wb - 64; int layer = b / 12; int rem = b % 12; int kt = rem / 3; int nt = rem % 3;
            if (nt < 2) { src = off_w + (size_t)layer * 256 * 128 + (size_t)kt * 64 * 128 + nt * 64; srcStride = 128; }
            else        { src = aw_w  + (size_t)layer * 256 * 64  + (size_t)kt * 64 * 64;            srcStride = 64;  }
            dstF = woffaw + (size_t)layer * 49152; ntb = nt * 4; kcb = kt * 2;
        } else {
            int b = wb - 112; int fam = b >> 6; int bb = b & 63;
            int layer = bb >> 4; int kt = (bb >> 2) & 3; int nt = bb & 3;
            const float* s0 = (fam == 0) ? out_w : ((fam == 1) ? f1_w : f2_w);
            ushort* d0      = (fam == 0) ? wout  : ((fam == 1) ? wf1  : wf2);
            src = s0 + (size_t)layer * 65536 + (size_t)kt * 64 * 256 + nt * 64; srcStride = 256;
            dstF = d0 + (size_t)layer * 65536; ntb = nt * 4; kcb = kt * 2;
        }
        int r = t >> 6, c = t & 63;
        #pragma unroll
        for (int rr = 0; rr < 64; rr += 4)                 // tl[k_local][n_local]
            tl[rr + r][c] = src[(size_t)(rr + r) * srcStride + c];
        __syncthreads();
        int l = t >> 2;               // 0..63 (lane of fragment)
        int e0 = (t & 3) * 2;         // 0,2,4,6
        int frow = l & 15;            // n within 16-tile
        int fcol = (l >> 4) * 8;      // k offset within chunk
        #pragma unroll
        for (int s = 0; s < 8; s++) {
            int ntl = s & 3, kcl = s >> 2;
            int ntile = ntb + ntl, kc = kcb + kcl;
            ushort2 val;
            val.x = f2bu(tl[kcl * 32 + fcol + e0    ][ntl * 16 + frow]);
            val.y = f2bu(tl[kcl * 32 + fcol + e0 + 1][ntl * 16 + frow]);
            *(ushort2*)(dstF + (((size_t)ntile * 8 + kc) * 64 + l) * 8 + e0) = val;
        }
        return;
    }
    {                                       // fuse
        int fb = bid - 3444;
        int b = fb >> 8;
        int c0 = ((fb >> 6) & 3) * 64;
        int q0 = (fb & 63) * 64;
        int r = t >> 6, c = t & 63;
        #pragma unroll
        for (int rr = 0; rr < 64; rr += 4) {
            int ch = c0 + rr + r;
            float l0 = fl[ch], l1 = fl[CC + ch];
            float m = fmaxf(l0, l1);
            float e0 = __expf(l0 - m), e1 = __expf(l1 - m);
            float inv = 1.0f / (e0 + e1);
            size_t o = ((size_t)b * CC + ch) * NQQ + q0 + c;
            tl[rr + r][c] = (feat0[o] * e0 + feat1[o] * e1) * inv;
        }
        __syncthreads();
        #pragma unroll
        for (int rr = 0; rr < 64; rr += 4)
            fused[((size_t)(b * NQQ + q0 + rr + r)) * CC + c0 + c] = f2bu(tl[c][rr + r]);
    }
}

// ======== projection GEMM: 32-row tiles, 1024 threads, 1 n-tile/wave, 2 row-groups ======
__global__ __launch_bounds__(1024, 4) void pgemm(const ushort* __restrict__ Abf,
        const ushort* __restrict__ Wf, const float* __restrict__ bias,
        ushort* __restrict__ Cb, int NS) {
    __shared__ ushort Abuf[32 * 264];
    const int t = threadIdx.x;
    const int m0 = blockIdx.x * 32;
    const int cb0 = blockIdx.y * 256;
    const int ntb = blockIdx.y * 16;
    {
        const int rg = t >> 5, c0 = (t & 31) * 8;
        *(int4*)(Abuf + rg * 264 + c0) = *(const int4*)(Abf + (size_t)(m0 + rg) * 256 + c0);
    }
    __syncthreads();
    const int l = t & 63, w = t >> 6;
    const int fr = l & 15, fk8 = (l >> 4) * 8, rb = (l >> 4) * 4;
    f4v acc[2] = {};
    #pragma unroll
    for (int kc = 0; kc < 8; kc++) {
        s8v b = *(const s8v*)(Wf + (((size_t)(ntb + w) * 8 + kc) * 64 + l) * 8);
        s8v a0 = *(const s8v*)(Abuf + fr * 264 + kc * 32 + fk8);
        s8v a1 = *(const s8v*)(Abuf + (16 + fr) * 264 + kc * 32 + fk8);
        acc[0] = __builtin_amdgcn_mfma_f32_16x16x32_bf16(a0, b, acc[0], 0, 0, 0);
        acc[1] = __builtin_amdgcn_mfma_f32_16x16x32_bf16(a1, b, acc[1], 0, 0, 0);
    }
    int gcol = cb0 + w * 16 + fr;
    float bz = bias[gcol];
    #pragma unroll
    for (int g = 0; g < 2; g++)
        #pragma unroll
        for (int r = 0; r < 4; r++)
            Cb[(size_t)(m0 + g * 16 + rb + r) * NS + gcol] = f2bu(acc[g][r] + bz);
}

// ======== full decoder layer: 32 rows/block, 1024 threads (16 waves), grid 256 ========
template<int SELF, int EMITVAL>
__global__ __launch_bounds__(1024, 4) void layer_kernel(
        float* __restrict__ tgt, const float* __restrict__ posq,
        const float* __restrict__ posY, const float* __restrict__ posX,
        const float* __restrict__ g1, const float* __restrict__ b1,
        const ushort* __restrict__ woffawL, const float* __restrict__ bOAL,
        const ushort* __restrict__ value, int vstride,
        const float* __restrict__ refp,
        const ushort* __restrict__ woutL, const float* __restrict__ out_bL,
        const float* __restrict__ g2, const float* __restrict__ b2,
        const ushort* __restrict__ wf1L, const float* __restrict__ f1_bL,
        const ushort* __restrict__ wf2L, const float* __restrict__ f2_bL,
        const ushort* __restrict__ wvalN, const float* __restrict__ val_bN,
        ushort* __restrict__ valueOut) {
    __shared__ ushort Abuf[32 * 264];          // 16.9 KB
    __shared__ float Slds[32 * 204];           // 26.1 KB
    __shared__ float pred[2][16][32];          // 4 KB
    __shared__ float mrs[2][32];
    const int t = threadIdx.x;
    const int m0 = blockIdx.x * 32;
    const int l = t & 63, w = t >> 6;          // wave 0..15
    const int fr = l & 15, fk8 = (l >> 4) * 8, rb = (l >> 4) * 4;
    const int gcol = w * 16 + fr;

    // ---- phase 0: stage query tile (LN1+qemb | +pos tables), 8 cols/thread ----
    {
        const int rg = t >> 5, c0 = (t & 31) * 8;
        int m = m0 + rg, q = m & (NQQ - 1);
        const float* src = tgt + (size_t)m * 256 + c0;
        float fv[8];
        *(float4*)&fv[0] = *(const float4*)src;
        *(float4*)&fv[4] = *(const float4*)(src + 4);
        if (!SELF) {
            float s = 0.0f;
            #pragma unroll
            for (int k = 0; k < 8; k++) s += fv[k];
            s += __shfl_xor(s, 1); s += __shfl_xor(s, 2); s += __shfl_xor(s, 4);
            s += __shfl_xor(s, 8); s += __shfl_xor(s, 16);
            float mean = s * (1.0f / 256.0f);
            float s2 = 0.0f;
            #pragma unroll
            for (int k = 0; k < 8; k++) { float d = fv[k] - mean; s2 += d * d; }
            s2 += __shfl_xor(s2, 1); s2 += __shfl_xor(s2, 2); s2 += __shfl_xor(s2, 4);
            s2 += __shfl_xor(s2, 8); s2 += __shfl_xor(s2, 16);
            float rstd = rsqrtf(s2 * (1.0f / 256.0f) + 1e-5f);
            const float* ep = posq + (size_t)q * 512 + c0;     // qemb[:, :C]
            #pragma unroll
            for (int k = 0; k < 8; k++)
                fv[k] = (fv[k] - mean) * rstd * g1[c0 + k] + b1[c0 + k] + ep[k];
        } else {
            const float* ep = (c0 < 128) ? (posY + (q >> 6) * 128 + c0)
                                         : (posX + (q & 63) * 128 + (c0 - 128));
            #pragma unroll
            for (int k = 0; k < 8; k++) fv[k] += ep[k];
        }
        ushort tmp[8];
        #pragma unroll
        for (int k = 0; k < 8; k++) tmp[k] = f2bu(fv[k]);
        *(int4*)(Abuf + rg * 264 + c0) = *(const int4*)tmp;
    }
    __syncthreads();

    // ---- phase 1: offaw GEMM (12 n-tiles, waves 0..11, 2 row-groups each) ----
    if (w < 12) {
        f4v oacc[2] = {};
        #pragma unroll
        for (int kc = 0; kc < 8; kc++) {
            s8v b = *(const s8v*)(woffawL + (((size_t)w * 8 + kc) * 64 + l) * 8);
            s8v a0 = *(const s8v*)(Abuf + fr * 264 + kc * 32 + fk8);
            s8v a1 = *(const s8v*)(Abuf + (16 + fr) * 264 + kc * 32 + fk8);
            oacc[0] = __builtin_amdgcn_mfma_f32_16x16x32_bf16(a0, b, oacc[0], 0, 0, 0);
            oacc[1] = __builtin_amdgcn_mfma_f32_16x16x32_bf16(a1, b, oacc[1], 0, 0, 0);
        }
        int ocol = w * 16 + fr;
        float bz = bOAL[ocol];
        #pragma unroll
        for (int g = 0; g < 2; g++)
            #pragma unroll
            for (int r = 0; r < 4; r++)
                Slds[(g * 16 + rb + r) * 204 + ocol] = oacc[g][r] + bz;
    }
    __syncthreads();

    // ---- phase 2: softmax + bilinear sampling; tail-prefetch residual tgt ----
    float tres[2][4];
    {
        const int row = t >> 5, h = (t >> 2) & 7, d8 = t & 3;
        int m = m0 + row, q = m & (NQQ - 1), bidx = m >> 12;
        float rxs, rys;
        if (SELF) { rxs = (float)(q & 63) * 64.0f + 32.0f; rys = (float)(q >> 6) * 64.0f + 32.0f; }
        else      { rxs = refp[q * 2] * 64.0f;             rys = refp[q * 2 + 1] * 64.0f; }
        const float* oa = Slds + row * 204;
        float lg[8];
        #pragma unroll
        for (int p = 0; p < 8; p++) lg[p] = oa[128 + h * 8 + p];
        float mx = lg[0];
        #pragma unroll
        for (int p = 1; p < 8; p++) mx = fmaxf(mx, lg[p]);
        float wg[8], wsum = 0.0f;
        #pragma unroll
        for (int p = 0; p < 8; p++) { wg[p] = __expf(lg[p] - mx); wsum += wg[p]; }
        float inv = 1.0f / wsum;
        const float* offp = oa + h * 16;
        const ushort* vb = value + (size_t)bidx * NQQ * vstride + h * 32 + d8 * 8;
        float acc[8] = {};
        #pragma unroll
        for (int p = 0; p < 8; p++) {
            float px = rxs + offp[p * 2]     - 0.5f;
            float py = rys + offp[p * 2 + 1] - 0.5f;
            float x0f = floorf(px), y0f = floorf(py);
            float lx = px - x0f, ly = py - y0f;
            int x0 = (int)x0f, y0 = (int)y0f;
            float wgt = wg[p] * inv;
            float w00 = (1 - lx) * (1 - ly) * wgt, w10 = lx * (1 - ly) * wgt;
            float w01 = (1 - lx) * ly * wgt,       w11 = lx * ly * wgt;
            #pragma unroll
            for (int cn = 0; cn < 4; cn++) {
                int xi = x0 + (cn & 1), yi = y0 + (cn >> 1);
                float wc = (cn == 0) ? w00 : (cn == 1) ? w10 : (cn == 2) ? w01 : w11;
                if (xi >= 0 && xi < 64 && yi >= 0 && yi < 64) {
                    uint4 uv = *(const uint4*)(vb + (size_t)(yi * 64 + xi) * vstride);
                    uint ua[4] = {uv.x, uv.y, uv.z, uv.w};
                    #pragma unroll
                    for (int k = 0; k < 4; k++) {
                        uint lo = ua[k] << 16;
                        uint hi = ua[k] & 0xffff0000u;
                        acc[k * 2 + 0] += wc * *reinterpret_cast<float*>(&lo);
                        acc[k * 2 + 1] += wc * *reinterpret_cast<float*>(&hi);
                    }
                }
            }
        }
        ushort pk[8];
        #pragma unroll
        for (int k = 0; k < 8; k++) pk[k] = f2bu(acc[k]);
        *(int4*)(Abuf + row * 264 + h * 32 + d8 * 8) = *(const int4*)pk;
        // tail-prefetch phase-3 residual reads (independent of Abuf/barrier)
        #pragma unroll
        for (int g = 0; g < 2; g++)
            #pragma unroll
            for (int r = 0; r < 4; r++)
                tres[g][r] = tgt[(size_t)(m0 + g * 16 + rb + r) * 256 + gcol];
    }
    __syncthreads();

    // ---- phase 3: out-proj + residual (v in regs) + LN2 stats ----
    float v[2][4];
    {
        f4v acc[2] = {};
        #pragma unroll
        for (int kc = 0; kc < 8; kc++) {
            s8v b = *(const s8v*)(woutL + (((size_t)w * 8 + kc) * 64 + l) * 8);
            s8v a0 = *(const s8v*)(Abuf + fr * 264 + kc * 32 + fk8);
            s8v a1 = *(const s8v*)(Abuf + (16 + fr) * 264 + kc * 32 + fk8);
            acc[0] = __builtin_amdgcn_mfma_f32_16x16x32_bf16(a0, b, acc[0], 0, 0, 0);
            acc[1] = __builtin_amdgcn_mfma_f32_16x16x32_bf16(a1, b, acc[1], 0, 0, 0);
        }
        float ls[2][4], lq[2][4];
        float bz = out_bL[gcol];
        #pragma unroll
        for (int g = 0; g < 2; g++)
            #pragma unroll
            for (int r = 0; r < 4; r++) {
                float tv = tres[g][r] + acc[g][r] + bz;
                v[g][r] = tv;
                ls[g][r] = tv;
                lq[g][r] = tv * tv;
            }
        #pragma unroll
        for (int o = 1; o < 16; o <<= 1)
            #pragma unroll
            for (int g = 0; g < 2; g++)
                #pragma unroll
                for (int r = 0; r < 4; r++) {
                    ls[g][r] += __shfl_xor(ls[g][r], o);
                    lq[g][r] += __shfl_xor(lq[g][r], o);
                }
        if (fr == 0)
            #pragma unroll
            for (int g = 0; g < 2; g++)
                #pragma unroll
                for (int r = 0; r < 4; r++) {
                    pred[0][w][g * 16 + rb + r] = ls[g][r];
                    pred[1][w][g * 16 + rb + r] = lq[g][r];
                }
    }
    __syncthreads();
    if (t < 32) {
        float s = 0.0f, sq = 0.0f;
        #pragma unroll
        for (int ww = 0; ww < 16; ww++) { s += pred[0][ww][t]; sq += pred[1][ww][t]; }
        float mean = s * (1.0f / 256.0f);
        float var = sq * (1.0f / 256.0f) - mean * mean;
        mrs[0][t] = mean;
        mrs[1][t] = rsqrtf(var + 1e-5f);
    }
    __syncthreads();

    // ---- LN2 normalize -> Abuf ----
    #pragma unroll
    for (int g = 0; g < 2; g++)
        #pragma unroll
        for (int r = 0; r < 4; r++) {
            int rloc = g * 16 + rb + r;
            Abuf[rloc * 264 + gcol] = f2bu((v[g][r] - mrs[0][rloc]) * mrs[1][rloc] * g2[gcol] + b2[gcol]);
        }
    __syncthreads();

    // ---- phase 4: FFN1 + relu -> Abuf ----
    {
        f4v acc[2] = {};
        #pragma unroll
        for (int kc = 0; kc < 8; kc++) {
            s8v b = *(const s8v*)(wf1L + (((size_t)w * 8 + kc) * 64 + l) * 8);
            s8v a0 = *(const s8v*)(Abuf + fr * 264 + kc * 32 + fk8);
            s8v a1 = *(const s8v*)(Abuf + (16 + fr) * 264 + kc * 32 + fk8);
            acc[0] = __builtin_amdgcn_mfma_f32_16x16x32_bf16(a0, b, acc[0], 0, 0, 0);
            acc[1] = __builtin_amdgcn_mfma_f32_16x16x32_bf16(a1, b, acc[1], 0, 0, 0);
        }
        __syncthreads();
        float bz = f1_bL[gcol];
        #pragma unroll
        for (int g = 0; g < 2; g++)
            #pragma unroll
            for (int r = 0; r < 4; r++)
                Abuf[(g * 16 + rb + r) * 264 + gcol] = f2bu(fmaxf(acc[g][r] + bz, 0.0f));
    }
    __syncthreads();

    // ---- phase 5: FFN2 + relu + residual, final write (+ restage if EMITVAL) ----
    {
        f4v acc[2] = {};
        #pragma unroll
        for (int kc = 0; kc < 8; kc++) {
            s8v b = *(const s8v*)(wf2L + (((size_t)w * 8 + kc) * 64 + l) * 8);
            s8v a0 = *(const s8v*)(Abuf + fr * 264 + kc * 32 + fk8);
            s8v a1 = *(const s8v*)(Abuf + (16 + fr) * 264 + kc * 32 + fk8);
            acc[0] = __builtin_amdgcn_mfma_f32_16x16x32_bf16(a0, b, acc[0], 0, 0, 0);
            acc[1] = __builtin_amdgcn_mfma_f32_16x16x32_bf16(a1, b, acc[1], 0, 0, 0);
        }
        if (EMITVAL) __syncthreads();       // drain Abuf reads before overwrite
        float bz = f2_bL[gcol];
        #pragma unroll
        for (int g = 0; g < 2; g++)
            #pragma unroll
            for (int r = 0; r < 4; r++) {
                float fin = v[g][r] + fmaxf(acc[g][r] + bz, 0.0f);
                tgt[(size_t)(m0 + g * 16 + rb + r) * 256 + gcol] = fin;
                if (EMITVAL) Abuf[(g * 16 + rb + r) * 264 + gcol] = f2bu(fin);
            }
    }
    if (EMITVAL) {
        __syncthreads();
        // ---- phase 6: next layer's value projection from in-LDS tgt ----
        f4v acc[2] = {};
        #pragma unroll
        for (int kc = 0; kc < 8; kc++) {
            s8v b = *(const s8v*)(wvalN + (((size_t)w * 8 + kc) * 64 + l) * 8);
            s8v a0 = *(const s8v*)(Abuf + fr * 264 + kc * 32 + fk8);
            s8v a1 = *(const s8v*)(Abuf + (16 + fr) * 264 + kc * 32 + fk8);
            acc[0] = __builtin_amdgcn_mfma_f32_16x16x32_bf16(a0, b, acc[0], 0, 0, 0);
            acc[1] = __builtin_amdgcn_mfma_f32_16x16x32_bf16(a1, b, acc[1], 0, 0, 0);
        }
        float bz = val_bN[gcol];
        #pragma unroll
        for (int g = 0; g < 2; g++)
            #pragma unroll
            for (int r = 0; r < 4; r++)
                valueOut[(size_t)(m0 + g * 16 + rb + r) * 256 + gcol] = f2bu(acc[g][r] + bz);
    }
}

extern "C" void kernel_launch(void* const* d_in, const int* in_sizes, int n_in,
                              void* d_out, int out_size, void* d_ws, size_t ws_size,
                              hipStream_t stream) {
    const float* feat0 = (const float*)d_in[0];
    const float* feat1 = (const float*)d_in[1];
    const float* qemb  = (const float*)d_in[2];
    const float* ref_w = (const float*)d_in[3];
    const float* ref_b = (const float*)d_in[4];
    const float* fl    = (const float*)d_in[5];
    const float* ln1_g = (const float*)d_in[6];
    const float* ln1_b = (const float*)d_in[7];
    const float* off_w = (const float*)d_in[8];
    const float* off_b = (const float*)d_in[9];
    const float* aw_w  = (const float*)d_in[10];
    const float* aw_b  = (const float*)d_in[11];
    const float* val_w = (const float*)d_in[12];
    const float* val_b = (const float*)d_in[13];
    const float* out_w = (const float*)d_in[14];
    const float* out_b = (const float*)d_in[15];
    const float* ln2_g = (const float*)d_in[16];
    const float* ln2_b = (const float*)d_in[17];
    const float* f1_w  = (const float*)d_in[18];
    const float* f1_b  = (const float*)d_in[19];
    const float* f2_w  = (const float*)d_in[20];
    const float* f2_b  = (const float*)d_in[21];

    float* tgt = (float*)d_out;
    float* ws = (float*)d_ws;
    float* posY    = ws;                                     // 8,192 f32
    float* posX    = posY + 8192;                            // 8,192 f32
    float* refp    = posX + 8192;                            // 8,192 f32
    float* bOA     = refp + 8192;                            // 768 f32
    ushort* value01= (ushort*)(bOA + 768);                   // MT*512
    ushort* valueS0= value01 + (size_t)MT * 512;             // MT*256
    ushort* valueS1= valueS0 + (size_t)MT * 256;             // MT*256
    ushort* wval01 = valueS1 + (size_t)MT * 256;             // 131072
    ushort* wvalS  = wval01 + 131072;                        // 131072
    ushort* woffaw = wvalS + 131072;                         // 196608
    ushort* wout   = woffaw + 196608;                        // 262144
    ushort* wf1    = wout + 262144;                          // 262144
    ushort* wf2    = wf1 + 262144;                           // 262144
    ushort* fused_bf = wf2 + 262144;                         // MT*256

    setup_kernel<<<3956, 256, 0, stream>>>(qemb, ref_w, ref_b, feat0, feat1, fl,
                                           val_w, off_w, aw_w, out_w, f1_w, f2_w,
                                           off_b, aw_b,
                                           posY, posX, refp, tgt,
                                           wval01, wvalS, woffaw, wout, wf1, wf2,
                                           bOA, fused_bf);

    // value projections for both cross layers: [MT,512] bf16
    pgemm<<<dim3(256, 2), 1024, 0, stream>>>(fused_bf, wval01, val_b, value01, 512);

    // L0 (cross)
    layer_kernel<0, 0><<<256, 1024, 0, stream>>>(
        tgt, qemb, posY, posX, ln1_g, ln1_b,
        woffaw, bOA, value01, 512, refp,
        wout, out_b, ln2_g, ln2_b,
        wf1, f1_b, wf2, f2_b,
        nullptr, nullptr, nullptr);
    // L1 (cross, emit value for L2)
    layer_kernel<0, 1><<<256, 1024, 0, stream>>>(
        tgt, qemb, posY, posX, ln1_g + CC, ln1_b + CC,
        woffaw + 49152, bOA + 192, value01 + 256, 512, refp,
        wout + 65536, out_b + CC, ln2_g + CC, ln2_b + CC,
        wf1 + 65536, f1_b + CC, wf2 + 65536, f2_b + CC,
        wvalS, val_b + 2 * CC, valueS0);
    // L2 (self, emit value for L3)
    layer_kernel<1, 1><<<256, 1024, 0, stream>>>(
        tgt, nullptr, posY, posX, nullptr, nullptr,
        woffaw + 2 * 49152, bOA + 2 * 192, valueS0, 256, refp,
        wout + 2 * 65536, out_b + 2 * CC, ln2_g + 2 * CC, ln2_b + 2 * CC,
        wf1 + 2 * 65536, f1_b + 2 * CC, wf2 + 2 * 65536, f2_b + 2 * CC,
        wvalS + 65536, val_b + 3 * CC, valueS1);
    // L3 (self)
    layer_kernel<1, 0><<<256, 1024, 0, stream>>>(
        tgt, nullptr, posY, posX, nullptr, nullptr,
        woffaw + 3 * 49152, bOA + 3 * 192, valueS1, 256, refp,
        wout + 3 * 65536, out_b + 3 * CC, ln2_g + 3 * CC, ln2_b + 3 * CC,
        wf1 + 3 * 65536, f1_b + 3 * CC, wf2 + 3 * 65536, f2_b + 3 * CC,
        nullptr, nullptr, nullptr);
}

// Round 13
// 111.739 us; speedup vs baseline: 1.0900x; 1.0346x over previous
//
#include <hip/hip_runtime.h>
#include <hip/hip_bf16.h>
#include <math.h>

#define CC   256
#define NQQ  4096
#define MT   8192

typedef __attribute__((ext_vector_type(8))) short s8v;
typedef __attribute__((ext_vector_type(4))) float f4v;

static __device__ __forceinline__ ushort f2bu(float f) {
    __hip_bfloat16 h = __float2bfloat16(f);
    return *reinterpret_cast<ushort*>(&h);
}

// Fragment layout for weights: Wf[((ntile*8 + kc)*64 + lane)*8 + e]
//   lane l supplies B rows (n = ntile*16 + (l&15)), k = kc*32 + (l>>4)*8 + e

// ======== setup: pos tables/refpts + weight->fragment transpose + fuse ========
__global__ __launch_bounds__(256) void setup_kernel(
        const float* __restrict__ qemb, const float* __restrict__ rw,
        const float* __restrict__ rb,
        const float* __restrict__ feat0, const float* __restrict__ feat1,
        const float* __restrict__ fl,
        const float* __restrict__ val_w, const float* __restrict__ off_w,
        const float* __restrict__ aw_w,  const float* __restrict__ out_w,
        const float* __restrict__ f1_w,  const float* __restrict__ f2_w,
        const float* __restrict__ off_b, const float* __restrict__ aw_b,
        float* __restrict__ posY, float* __restrict__ posX,
        float* __restrict__ refp,
        ushort* __restrict__ wval01, ushort* __restrict__ wvalS,
        ushort* __restrict__ woffaw, ushort* __restrict__ wout,
        ushort* __restrict__ wf1, ushort* __restrict__ wf2,
        float* __restrict__ bOA, ushort* __restrict__ fused) {
    __shared__ float tl[64][65];
    int bid = blockIdx.x;
    int t = threadIdx.x;
    if (bid < 64) {                         // pos tables: posY[64][128], posX[64][128]
        int idx = bid * 256 + t;            // 0..16383
        int tbl = idx >> 13;
        int rem = idx & 8191;
        int ci = rem >> 7;                  // coord index 0..63
        int c = rem & 127;
        int k = c >> 1;
        float coord = (float)(ci + 1) * (6.28318530717958647692f / (64.0f + 1e-6f));
        float v = coord * exp2f(-0.20762050593046016f * (float)k);
        float val = (c & 1) ? __cosf(v) : __sinf(v);
        (tbl == 0 ? posY : posX)[ci * 128 + c] = val;
        return;
    }
    if (bid < 1088) {                       // refpts
        int row = (bid - 64) * 4 + (t >> 6);
        int l = t & 63;
        float4 v = *(const float4*)(qemb + (size_t)row * 512 + l * 4);
        float a0 = v.x * rw[(l * 4 + 0) * 2] + v.y * rw[(l * 4 + 1) * 2]
                 + v.z * rw[(l * 4 + 2) * 2] + v.w * rw[(l * 4 + 3) * 2];
        float a1 = v.x * rw[(l * 4 + 0) * 2 + 1] + v.y * rw[(l * 4 + 1) * 2 + 1]
                 + v.z * rw[(l * 4 + 2) * 2 + 1] + v.w * rw[(l * 4 + 3) * 2 + 1];
        #pragma unroll
        for (int o = 32; o > 0; o >>= 1) { a0 += __shfl_xor(a0, o); a1 += __shfl_xor(a1, o); }
        if (l == 0) {
            refp[row * 2 + 0] = 1.0f / (1.0f + __expf(-(a0 + rb[0])));
            refp[row * 2 + 1] = 1.0f / (1.0f + __expf(-(a1 + rb[1])));
        }
        return;
    }
    if (bid < 1396) {                       // weight prep -> fragment layout
        int wb = bid - 1088;
        if (wb >= 304) {
            int layer = wb - 304;
            if (t < 192)
                bOA[layer * 192 + t] = (t < 128) ? off_b[layer * 128 + t]
                                                 : aw_b[layer * 64 + (t - 128)];
            return;
        }
        const float* src; ushort* dstF; int srcStride, ntb, kcb;
        if (wb < 32) {
            int nt = wb & 7, kt = wb >> 3;
            int layer = nt >> 2, nn = (nt & 3) * 64;
            src = val_w + (size_t)layer * 65536 + (size_t)kt * 64 * 256 + nn; srcStride = 256;
            dstF = wval01; ntb = nt * 4; kcb = kt * 2;
        } else if (wb < 64) {
            int b = wb - 32; int layer = b >> 4; int kt = (b >> 2) & 3; int nt = b & 3;
            src = val_w + (size_t)(2 + layer) * 65536 + (size_t)kt * 64 * 256 + nt * 64; srcStride = 256;
            dstF = wvalS + (size_t)layer * 65536; ntb = nt * 4; kcb = kt * 2;
        } else if (wb < 112) {
            int b = wb - 64; int layer = b / 12; int rem = b % 12; int kt = rem / 3; int nt = rem % 3;
            if (nt < 2) { src = off_w + (size_t)layer * 256 * 128 + (size_t)kt * 64 * 128 + nt * 64; srcStride = 128; }
            else        { src = aw_w  + (size_t)layer * 256 * 64  + (size_t)kt * 64 * 64;            srcStride = 64;  }
            dstF = woffaw + (size_t)layer * 49152; ntb = nt * 4; kcb = kt * 2;
        } else {
            int b = wb - 112; int fam = b >> 6; int bb = b & 63;
            int layer = bb >> 4; int kt = (bb >> 2) & 3; int nt = bb & 3;
            const float* s0 = (fam == 0) ? out_w : ((fam == 1) ? f1_w : f2_w);
            ushort* d0      = (fam == 0) ? wout  : ((fam == 1) ? wf1  : wf2);
            src = s0 + (size_t)layer * 65536 + (size_t)kt * 64 * 256 + nt * 64; srcStride = 256;
            dstF = d0 + (size_t)layer * 65536; ntb = nt * 4; kcb = kt * 2;
        }
        int r = t >> 6, c = t & 63;
        #pragma unroll
        for (int rr = 0; rr < 64; rr += 4)                 // tl[k_local][n_local]
            tl[rr + r][c] = src[(size_t)(rr + r) * srcStride + c];
        __syncthreads();
        int l = t >> 2;               // 0..63 (lane of fragment)
        int e0 = (t & 3) * 2;         // 0,2,4,6
        int frow = l & 15;            // n within 16-tile
        int fcol = (l >> 4) * 8;      // k offset within chunk
        #pragma unroll
        for (int s = 0; s < 8; s++) {
            int ntl = s & 3, kcl = s >> 2;
            int ntile = ntb + ntl, kc = kcb + kcl;
            ushort2 val;
            val.x = f2bu(tl[kcl * 32 + fcol + e0    ][ntl * 16 + frow]);
            val.y = f2bu(tl[kcl * 32 + fcol + e0 + 1][ntl * 16 + frow]);
            *(ushort2*)(dstF + (((size_t)ntile * 8 + kc) * 64 + l) * 8 + e0) = val;
        }
        return;
    }
    {                                       // fuse
        int fb = bid - 1396;
        int b = fb >> 8;
        int c0 = ((fb >> 6) & 3) * 64;
        int q0 = (fb & 63) * 64;
        int r = t >> 6, c = t & 63;
        #pragma unroll
        for (int rr = 0; rr < 64; rr += 4) {
            int ch = c0 + rr + r;
            float l0 = fl[ch], l1 = fl[CC + ch];
            float m = fmaxf(l0, l1);
            float e0 = __expf(l0 - m), e1 = __expf(l1 - m);
            float inv = 1.0f / (e0 + e1);
            size_t o = ((size_t)b * CC + ch) * NQQ + q0 + c;
            tl[rr + r][c] = (feat0[o] * e0 + feat1[o] * e1) * inv;
        }
        __syncthreads();
        #pragma unroll
        for (int rr = 0; rr < 64; rr += 4)
            fused[((size_t)(b * NQQ + q0 + rr + r)) * CC + c0 + c] = f2bu(tl[c][rr + r]);
    }
}

// ======== projection GEMM: 32-row tiles, 1024 threads, 1 n-tile/wave, 2 row-groups ======
__global__ __launch_bounds__(1024, 4) void pgemm(const ushort* __restrict__ Abf,
        const ushort* __restrict__ Wf, const float* __restrict__ bias,
        ushort* __restrict__ Cb, int NS) {
    __shared__ ushort Abuf[32 * 264];
    const int t = threadIdx.x;
    const int m0 = blockIdx.x * 32;
    const int cb0 = blockIdx.y * 256;
    const int ntb = blockIdx.y * 16;
    {
        const int rg = t >> 5, c0 = (t & 31) * 8;
        *(int4*)(Abuf + rg * 264 + c0) = *(const int4*)(Abf + (size_t)(m0 + rg) * 256 + c0);
    }
    __syncthreads();
    const int l = t & 63, w = t >> 6;
    const int fr = l & 15, fk8 = (l >> 4) * 8, rb = (l >> 4) * 4;
    f4v acc[2] = {};
    #pragma unroll
    for (int kc = 0; kc < 8; kc++) {
        s8v b = *(const s8v*)(Wf + (((size_t)(ntb + w) * 8 + kc) * 64 + l) * 8);
        s8v a0 = *(const s8v*)(Abuf + fr * 264 + kc * 32 + fk8);
        s8v a1 = *(const s8v*)(Abuf + (16 + fr) * 264 + kc * 32 + fk8);
        acc[0] = __builtin_amdgcn_mfma_f32_16x16x32_bf16(a0, b, acc[0], 0, 0, 0);
        acc[1] = __builtin_amdgcn_mfma_f32_16x16x32_bf16(a1, b, acc[1], 0, 0, 0);
    }
    int gcol = cb0 + w * 16 + fr;
    float bz = bias[gcol];
    #pragma unroll
    for (int g = 0; g < 2; g++)
        #pragma unroll
        for (int r = 0; r < 4; r++)
            Cb[(size_t)(m0 + g * 16 + rb + r) * NS + gcol] = f2bu(acc[g][r] + bz);
}

// ======== full decoder layer: 32 rows/block, 1024 threads (16 waves), grid 256 ========
// TGTINIT=1 (L0 only): tgt not yet initialized; read qemb[:,C:] instead (b-broadcast),
// first actual tgt write is phase 5.
template<int SELF, int EMITVAL, int TGTINIT>
__global__ __launch_bounds__(1024, 4) void layer_kernel(
        float* __restrict__ tgt, const float* __restrict__ posq,
        const float* __restrict__ posY, const float* __restrict__ posX,
        const float* __restrict__ g1, const float* __restrict__ b1,
        const ushort* __restrict__ woffawL, const float* __restrict__ bOAL,
        const ushort* __restrict__ value, int vstride,
        const float* __restrict__ refp,
        const ushort* __restrict__ woutL, const float* __restrict__ out_bL,
        const float* __restrict__ g2, const float* __restrict__ b2,
        const ushort* __restrict__ wf1L, const float* __restrict__ f1_bL,
        const ushort* __restrict__ wf2L, const float* __restrict__ f2_bL,
        const ushort* __restrict__ wvalN, const float* __restrict__ val_bN,
        ushort* __restrict__ valueOut) {
    __shared__ ushort Abuf[32 * 264];          // 16.9 KB
    __shared__ float Slds[32 * 204];           // 26.1 KB
    __shared__ float pred[2][16][32];          // 4 KB
    __shared__ float mrs[2][32];
    const int t = threadIdx.x;
    const int m0 = blockIdx.x * 32;
    const int l = t & 63, w = t >> 6;          // wave 0..15
    const int fr = l & 15, fk8 = (l >> 4) * 8, rb = (l >> 4) * 4;
    const int gcol = w * 16 + fr;

    // ---- phase 0: stage query tile (LN1+qemb | +pos tables), 8 cols/thread ----
    {
        const int rg = t >> 5, c0 = (t & 31) * 8;
        int m = m0 + rg, q = m & (NQQ - 1);
        const float* src = TGTINIT ? (posq + (size_t)q * 512 + 256 + c0)
                                   : (tgt + (size_t)m * 256 + c0);
        float fv[8];
        *(float4*)&fv[0] = *(const float4*)src;
        *(float4*)&fv[4] = *(const float4*)(src + 4);
        if (!SELF) {
            float s = 0.0f;
            #pragma unroll
            for (int k = 0; k < 8; k++) s += fv[k];
            s += __shfl_xor(s, 1); s += __shfl_xor(s, 2); s += __shfl_xor(s, 4);
            s += __shfl_xor(s, 8); s += __shfl_xor(s, 16);
            float mean = s * (1.0f / 256.0f);
            float s2 = 0.0f;
            #pragma unroll
            for (int k = 0; k < 8; k++) { float d = fv[k] - mean; s2 += d * d; }
            s2 += __shfl_xor(s2, 1); s2 += __shfl_xor(s2, 2); s2 += __shfl_xor(s2, 4);
            s2 += __shfl_xor(s2, 8); s2 += __shfl_xor(s2, 16);
            float rstd = rsqrtf(s2 * (1.0f / 256.0f) + 1e-5f);
            const float* ep = posq + (size_t)q * 512 + c0;     // qemb[:, :C]
            #pragma unroll
            for (int k = 0; k < 8; k++)
                fv[k] = (fv[k] - mean) * rstd * g1[c0 + k] + b1[c0 + k] + ep[k];
        } else {
            const float* ep = (c0 < 128) ? (posY + (q >> 6) * 128 + c0)
                                         : (posX + (q & 63) * 128 + (c0 - 128));
            #pragma unroll
            for (int k = 0; k < 8; k++) fv[k] += ep[k];
        }
        ushort tmp[8];
        #pragma unroll
        for (int k = 0; k < 8; k++) tmp[k] = f2bu(fv[k]);
        *(int4*)(Abuf + rg * 264 + c0) = *(const int4*)tmp;
    }
    __syncthreads();

    // ---- phase 1: offaw GEMM (12 n-tiles, waves 0..11, 2 row-groups each) ----
    if (w < 12) {
        f4v oacc[2] = {};
        #pragma unroll
        for (int kc = 0; kc < 8; kc++) {
            s8v b = *(const s8v*)(woffawL + (((size_t)w * 8 + kc) * 64 + l) * 8);
            s8v a0 = *(const s8v*)(Abuf + fr * 264 + kc * 32 + fk8);
            s8v a1 = *(const s8v*)(Abuf + (16 + fr) * 264 + kc * 32 + fk8);
            oacc[0] = __builtin_amdgcn_mfma_f32_16x16x32_bf16(a0, b, oacc[0], 0, 0, 0);
            oacc[1] = __builtin_amdgcn_mfma_f32_16x16x32_bf16(a1, b, oacc[1], 0, 0, 0);
        }
        int ocol = w * 16 + fr;
        float bz = bOAL[ocol];
        #pragma unroll
        for (int g = 0; g < 2; g++)
            #pragma unroll
            for (int r = 0; r < 4; r++)
                Slds[(g * 16 + rb + r) * 204 + ocol] = oacc[g][r] + bz;
    }
    __syncthreads();

    // ---- phase 2: softmax + bilinear sampling; tail-prefetch residual ----
    float tres[2][4];
    {
        const int row = t >> 5, h = (t >> 2) & 7, d8 = t & 3;
        int m = m0 + row, q = m & (NQQ - 1), bidx = m >> 12;
        float rxs, rys;
        if (SELF) { rxs = (float)(q & 63) * 64.0f + 32.0f; rys = (float)(q >> 6) * 64.0f + 32.0f; }
        else      { rxs = refp[q * 2] * 64.0f;             rys = refp[q * 2 + 1] * 64.0f; }
        const float* oa = Slds + row * 204;
        float lg[8];
        #pragma unroll
        for (int p = 0; p < 8; p++) lg[p] = oa[128 + h * 8 + p];
        float mx = lg[0];
        #pragma unroll
        for (int p = 1; p < 8; p++) mx = fmaxf(mx, lg[p]);
        float wg[8], wsum = 0.0f;
        #pragma unroll
        for (int p = 0; p < 8; p++) { wg[p] = __expf(lg[p] - mx); wsum += wg[p]; }
        float inv = 1.0f / wsum;
        const float* offp = oa + h * 16;
        const ushort* vb = value + (size_t)bidx * NQQ * vstride + h * 32 + d8 * 8;
        float acc[8] = {};
        #pragma unroll
        for (int p = 0; p < 8; p++) {
            float px = rxs + offp[p * 2]     - 0.5f;
            float py = rys + offp[p * 2 + 1] - 0.5f;
            float x0f = floorf(px), y0f = floorf(py);
            float lx = px - x0f, ly = py - y0f;
            int x0 = (int)x0f, y0 = (int)y0f;
            float wgt = wg[p] * inv;
            float w00 = (1 - lx) * (1 - ly) * wgt, w10 = lx * (1 - ly) * wgt;
            float w01 = (1 - lx) * ly * wgt,       w11 = lx * ly * wgt;
            #pragma unroll
            for (int cn = 0; cn < 4; cn++) {
                int xi = x0 + (cn & 1), yi = y0 + (cn >> 1);
                float wc = (cn == 0) ? w00 : (cn == 1) ? w10 : (cn == 2) ? w01 : w11;
                if (xi >= 0 && xi < 64 && yi >= 0 && yi < 64) {
                    uint4 uv = *(const uint4*)(vb + (size_t)(yi * 64 + xi) * vstride);
                    uint ua[4] = {uv.x, uv.y, uv.z, uv.w};
                    #pragma unroll
                    for (int k = 0; k < 4; k++) {
                        uint lo = ua[k] << 16;
                        uint hi = ua[k] & 0xffff0000u;
                        acc[k * 2 + 0] += wc * *reinterpret_cast<float*>(&lo);
                        acc[k * 2 + 1] += wc * *reinterpret_cast<float*>(&hi);
                    }
                }
            }
        }
        ushort pk[8];
        #pragma unroll
        for (int k = 0; k < 8; k++) pk[k] = f2bu(acc[k]);
        *(int4*)(Abuf + row * 264 + h * 32 + d8 * 8) = *(const int4*)pk;
        // tail-prefetch phase-3 residual reads (independent of Abuf/barrier)
        #pragma unroll
        for (int g = 0; g < 2; g++)
            #pragma unroll
            for (int r = 0; r < 4; r++) {
                int mm = m0 + g * 16 + rb + r;
                tres[g][r] = TGTINIT ? posq[(size_t)(mm & (NQQ - 1)) * 512 + 256 + gcol]
                                     : tgt[(size_t)mm * 256 + gcol];
            }
    }
    __syncthreads();

    // ---- phase 3: out-proj + residual (v in regs) + LN2 stats ----
    float v[2][4];
    {
        f4v acc[2] = {};
        #pragma unroll
        for (int kc = 0; kc < 8; kc++) {
            s8v b = *(const s8v*)(woutL + (((size_t)w * 8 + kc) * 64 + l) * 8);
            s8v a0 = *(const s8v*)(Abuf + fr * 264 + kc * 32 + fk8);
            s8v a1 = *(const s8v*)(Abuf + (16 + fr) * 264 + kc * 32 + fk8);
            acc[0] = __builtin_amdgcn_mfma_f32_16x16x32_bf16(a0, b, acc[0], 0, 0, 0);
            acc[1] = __builtin_amdgcn_mfma_f32_16x16x32_bf16(a1, b, acc[1], 0, 0, 0);
        }
        float ls[2][4], lq[2][4];
        float bz = out_bL[gcol];
        #pragma unroll
        for (int g = 0; g < 2; g++)
            #pragma unroll
            for (int r = 0; r < 4; r++) {
                float tv = tres[g][r] + acc[g][r] + bz;
                v[g][r] = tv;
                ls[g][r] = tv;
                lq[g][r] = tv * tv;
            }
        #pragma unroll
        for (int o = 1; o < 16; o <<= 1)
            #pragma unroll
            for (int g = 0; g < 2; g++)
                #pragma unroll
                for (int r = 0; r < 4; r++) {
                    ls[g][r] += __shfl_xor(ls[g][r], o);
                    lq[g][r] += __shfl_xor(lq[g][r], o);
                }
        if (fr == 0)
            #pragma unroll
            for (int g = 0; g < 2; g++)
                #pragma unroll
                for (int r = 0; r < 4; r++) {
                    pred[0][w][g * 16 + rb + r] = ls[g][r];
                    pred[1][w][g * 16 + rb + r] = lq[g][r];
                }
    }
    __syncthreads();
    if (t < 32) {
        float s = 0.0f, sq = 0.0f;
        #pragma unroll
        for (int ww = 0; ww < 16; ww++) { s += pred[0][ww][t]; sq += pred[1][ww][t]; }
        float mean = s * (1.0f / 256.0f);
        float var = sq * (1.0f / 256.0f) - mean * mean;
        mrs[0][t] = mean;
        mrs[1][t] = rsqrtf(var + 1e-5f);
    }
    __syncthreads();

    // ---- LN2 normalize -> Abuf ----
    #pragma unroll
    for (int g = 0; g < 2; g++)
        #pragma unroll
        for (int r = 0; r < 4; r++) {
            int rloc = g * 16 + rb + r;
            Abuf[rloc * 264 + gcol] = f2bu((v[g][r] - mrs[0][rloc]) * mrs[1][rloc] * g2[gcol] + b2[gcol]);
        }
    __syncthreads();

    // ---- phase 4: FFN1 + relu -> Abuf ----
    {
        f4v acc[2] = {};
        #pragma unroll
        for (int kc = 0; kc < 8; kc++) {
            s8v b = *(const s8v*)(wf1L + (((size_t)w * 8 + kc) * 64 + l) * 8);
            s8v a0 = *(const s8v*)(Abuf + fr * 264 + kc * 32 + fk8);
            s8v a1 = *(const s8v*)(Abuf + (16 + fr) * 264 + kc * 32 + fk8);
            acc[0] = __builtin_amdgcn_mfma_f32_16x16x32_bf16(a0, b, acc[0], 0, 0, 0);
            acc[1] = __builtin_amdgcn_mfma_f32_16x16x32_bf16(a1, b, acc[1], 0, 0, 0);
        }
        __syncthreads();
        float bz = f1_bL[gcol];
        #pragma unroll
        for (int g = 0; g < 2; g++)
            #pragma unroll
            for (int r = 0; r < 4; r++)
                Abuf[(g * 16 + rb + r) * 264 + gcol] = f2bu(fmaxf(acc[g][r] + bz, 0.0f));
    }
    __syncthreads();

    // ---- phase 5: FFN2 + relu + residual, final write (+ restage if EMITVAL) ----
    {
        f4v acc[2] = {};
        #pragma unroll
        for (int kc = 0; kc < 8; kc++) {
            s8v b = *(const s8v*)(wf2L + (((size_t)w * 8 + kc) * 64 + l) * 8);
            s8v a0 = *(const s8v*)(Abuf + fr * 264 + kc * 32 + fk8);
            s8v a1 = *(const s8v*)(Abuf + (16 + fr) * 264 + kc * 32 + fk8);
            acc[0] = __builtin_amdgcn_mfma_f32_16x16x32_bf16(a0, b, acc[0], 0, 0, 0);
            acc[1] = __builtin_amdgcn_mfma_f32_16x16x32_bf16(a1, b, acc[1], 0, 0, 0);
        }
        if (EMITVAL) __syncthreads();       // drain Abuf reads before overwrite
        float bz = f2_bL[gcol];
        #pragma unroll
        for (int g = 0; g < 2; g++)
            #pragma unroll
            for (int r = 0; r < 4; r++) {
                float fin = v[g][r] + fmaxf(acc[g][r] + bz, 0.0f);
                tgt[(size_t)(m0 + g * 16 + rb + r) * 256 + gcol] = fin;
                if (EMITVAL) Abuf[(g * 16 + rb + r) * 264 + gcol] = f2bu(fin);
            }
    }
    if (EMITVAL) {
        __syncthreads();
        // ---- phase 6: next layer's value projection from in-LDS tgt ----
        f4v acc[2] = {};
        #pragma unroll
        for (int kc = 0; kc < 8; kc++) {
            s8v b = *(const s8v*)(wvalN + (((size_t)w * 8 + kc) * 64 + l) * 8);
            s8v a0 = *(const s8v*)(Abuf + fr * 264 + kc * 32 + fk8);
            s8v a1 = *(const s8v*)(Abuf + (16 + fr) * 264 + kc * 32 + fk8);
            acc[0] = __builtin_amdgcn_mfma_f32_16x16x32_bf16(a0, b, acc[0], 0, 0, 0);
            acc[1] = __builtin_amdgcn_mfma_f32_16x16x32_bf16(a1, b, acc[1], 0, 0, 0);
        }
        float bz = val_bN[gcol];
        #pragma unroll
        for (int g = 0; g < 2; g++)
            #pragma unroll
            for (int r = 0; r < 4; r++)
                valueOut[(size_t)(m0 + g * 16 + rb + r) * 256 + gcol] = f2bu(acc[g][r] + bz);
    }
}

extern "C" void kernel_launch(void* const* d_in, const int* in_sizes, int n_in,
                              void* d_out, int out_size, void* d_ws, size_t ws_size,
                              hipStream_t stream) {
    const float* feat0 = (const float*)d_in[0];
    const float* feat1 = (const float*)d_in[1];
    const float* qemb  = (const float*)d_in[2];
    const float* ref_w = (const float*)d_in[3];
    const float* ref_b = (const float*)d_in[4];
    const float* fl    = (const float*)d_in[5];
    const float* ln1_g = (const float*)d_in[6];
    const float* ln1_b = (const float*)d_in[7];
    const float* off_w = (const float*)d_in[8];
    const float* off_b = (const float*)d_in[9];
    const float* aw_w  = (const float*)d_in[10];
    const float* aw_b  = (const float*)d_in[11];
    const float* val_w = (const float*)d_in[12];
    const float* val_b = (const float*)d_in[13];
    const float* out_w = (const float*)d_in[14];
    const float* out_b = (const float*)d_in[15];
    const float* ln2_g = (const float*)d_in[16];
    const float* ln2_b = (const float*)d_in[17];
    const float* f1_w  = (const float*)d_in[18];
    const float* f1_b  = (const float*)d_in[19];
    const float* f2_w  = (const float*)d_in[20];
    const float* f2_b  = (const float*)d_in[21];

    float* tgt = (float*)d_out;
    float* ws = (float*)d_ws;
    float* posY    = ws;                                     // 8,192 f32
    float* posX    = posY + 8192;                            // 8,192 f32
    float* refp    = posX + 8192;                            // 8,192 f32
    float* bOA     = refp + 8192;                            // 768 f32
    ushort* value01= (ushort*)(bOA + 768);                   // MT*512
    ushort* valueS0= value01 + (size_t)MT * 512;             // MT*256
    ushort* valueS1= valueS0 + (size_t)MT * 256;             // MT*256
    ushort* wval01 = valueS1 + (size_t)MT * 256;             // 131072
    ushort* wvalS  = wval01 + 131072;                        // 131072
    ushort* woffaw = wvalS + 131072;                         // 196608
    ushort* wout   = woffaw + 196608;                        // 262144
    ushort* wf1    = wout + 262144;                          // 262144
    ushort* wf2    = wf1 + 262144;                           // 262144
    ushort* fused_bf = wf2 + 262144;                         // MT*256

    setup_kernel<<<1908, 256, 0, stream>>>(qemb, ref_w, ref_b, feat0, feat1, fl,
                                           val_w, off_w, aw_w, out_w, f1_w, f2_w,
                                           off_b, aw_b,
                                           posY, posX, refp,
                                           wval01, wvalS, woffaw, wout, wf1, wf2,
                                           bOA, fused_bf);

    // value projections for both cross layers: [MT,512] bf16
    pgemm<<<dim3(256, 2), 1024, 0, stream>>>(fused_bf, wval01, val_b, value01, 512);

    // L0 (cross, tgt-init fused: reads qemb directly)
    layer_kernel<0, 0, 1><<<256, 1024, 0, stream>>>(
        tgt, qemb, posY, posX, ln1_g, ln1_b,
        woffaw, bOA, value01, 512, refp,
        wout, out_b, ln2_g, ln2_b,
        wf1, f1_b, wf2, f2_b,
        nullptr, nullptr, nullptr);
    // L1 (cross, emit value for L2)
    layer_kernel<0, 1, 0><<<256, 1024, 0, stream>>>(
        tgt, qemb, posY, posX, ln1_g + CC, ln1_b + CC,
        woffaw + 49152, bOA + 192, value01 + 256, 512, refp,
        wout + 65536, out_b + CC, ln2_g + CC, ln2_b + CC,
        wf1 + 65536, f1_b + CC, wf2 + 65536, f2_b + CC,
        wvalS, val_b + 2 * CC, valueS0);
    // L2 (self, emit value for L3)
    layer_kernel<1, 1, 0><<<256, 1024, 0, stream>>>(
        tgt, nullptr, posY, posX, nullptr, nullptr,
        woffaw + 2 * 49152, bOA + 2 * 192, valueS0, 256, refp,
        wout + 2 * 65536, out_b + 2 * CC, ln2_g + 2 * CC, ln2_b + 2 * CC,
        wf1 + 2 * 65536, f1_b + 2 * CC, wf2 + 2 * 65536, f2_b + 2 * CC,
        wvalS + 65536, val_b + 3 * CC, valueS1);
    // L3 (self)
    layer_kernel<1, 0, 0><<<256, 1024, 0, stream>>>(
        tgt, nullptr, posY, posX, nullptr, nullptr,
        woffaw + 3 * 49152, bOA + 3 * 192, valueS1, 256, refp,
        wout + 3 * 65536, out_b + 3 * CC, ln2_g + 3 * CC, ln2_b + 3 * CC,
        wf1 + 3 * 65536, f1_b + 3 * CC, wf2 + 3 * 65536, f2_b + 3 * CC,
        nullptr, nullptr, nullptr);
}